// Round 1
// baseline (1526.828 us; speedup 1.0000x reference)
//
#include <hip/hip_runtime.h>
#include <math.h>

#define B_ 4
#define N_ 1024
#define C_ 1024
#define H_ 16
#define D_ 64
#define BN_ 4096        // B*N rows
#define BH_ 64          // B*H
#define NUMEL_ 1048576  // N*N
#define KSMALL_ 104858u // numel - int(0.9*numel)  -> 1-based kth smallest
#define EPS_ 1e-5f

__device__ __forceinline__ unsigned f2key(float f) {
    unsigned u = __float_as_uint(f);
    return (u & 0x80000000u) ? ~u : (u | 0x80000000u);
}

// ---------------- LN row stats (mean, rstd) for q_inputs and kv_inputs ----------------
__global__ __launch_bounds__(256)
void ln_stats_kernel(const float* __restrict__ qin, const float* __restrict__ kvin,
                     float* __restrict__ stats)  // [mu_q(4096), rs_q, mu_kv, rs_kv]
{
    int row = blockIdx.x;              // 0..2*BN-1
    int tid = threadIdx.x;
    const float* x = (row < BN_) ? (qin + (size_t)row * C_) : (kvin + (size_t)(row - BN_) * C_);
    float4 v = ((const float4*)x)[tid];
    float s = v.x + v.y + v.z + v.w;
    float s2 = v.x*v.x + v.y*v.y + v.z*v.z + v.w*v.w;
    #pragma unroll
    for (int off = 32; off; off >>= 1) {
        s  += __shfl_down(s, off);
        s2 += __shfl_down(s2, off);
    }
    __shared__ float ls[4], ls2[4];
    int wid = tid >> 6;
    if ((tid & 63) == 0) { ls[wid] = s; ls2[wid] = s2; }
    __syncthreads();
    if (tid == 0) {
        float S  = ls[0] + ls[1] + ls[2] + ls[3];
        float S2 = ls2[0] + ls2[1] + ls2[2] + ls2[3];
        float mu = S * (1.0f / C_);
        float var = S2 * (1.0f / C_) - mu * mu;
        float rs = rsqrtf(var + EPS_);
        int base = (row < BN_) ? 0 : 2 * BN_;
        int r    = (row < BN_) ? row : row - BN_;
        stats[base + r] = mu;
        stats[base + BN_ + r] = rs;
    }
}

// ---------------- fused LN + projection GEMM:  out[b,h,n,d] = LN(x)[m,:] . W[o,:] + bias[o]
__global__ __launch_bounds__(256)
void proj_kernel(const float* __restrict__ qin, const float* __restrict__ kvin,
                 const float* __restrict__ stats,
                 const float* __restrict__ g_q, const float* __restrict__ b_q,
                 const float* __restrict__ g_k, const float* __restrict__ b_k,
                 const float* __restrict__ g_v, const float* __restrict__ b_v,
                 const float* __restrict__ Wq, const float* __restrict__ bq,
                 const float* __restrict__ Wk, const float* __restrict__ bk,
                 const float* __restrict__ Wv, const float* __restrict__ bv,
                 float* __restrict__ outq, float* __restrict__ outk, float* __restrict__ outv)
{
    int z = blockIdx.z;
    const float* X   = (z == 0) ? qin : kvin;
    const float* mu  = stats + ((z == 0) ? 0 : 2 * BN_);
    const float* rsd = mu + BN_;
    const float* g   = (z == 0) ? g_q : (z == 1 ? g_k : g_v);
    const float* be  = (z == 0) ? b_q : (z == 1 ? b_k : b_v);
    const float* W   = (z == 0) ? Wq  : (z == 1 ? Wk  : Wv);
    const float* bias= (z == 0) ? bq  : (z == 1 ? bk  : bv);
    float* out       = (z == 0) ? outq: (z == 1 ? outk: outv);

    int m0 = blockIdx.y * 64;
    int o0 = blockIdx.x * 64;
    int tid = threadIdx.x;

    __shared__ float As[64][20];   // row-major [m][k], stride 20 keeps float4 alignment
    __shared__ float Bs[64][20];   // [o][k]

    int lr = tid >> 2;             // 0..63
    int lc = (tid & 3) * 4;        // 0,4,8,12
    int tx = tid & 15, ty = tid >> 4;

    float mu_r = mu[m0 + lr];
    float rs_r = rsd[m0 + lr];

    float acc[4][4] = {};

    for (int k0 = 0; k0 < C_; k0 += 16) {
        float4 a  = *(const float4*)(X + (size_t)(m0 + lr) * C_ + k0 + lc);
        float4 gg = *(const float4*)(g  + k0 + lc);
        float4 bb = *(const float4*)(be + k0 + lc);
        float4 an;
        an.x = (a.x - mu_r) * rs_r * gg.x + bb.x;
        an.y = (a.y - mu_r) * rs_r * gg.y + bb.y;
        an.z = (a.z - mu_r) * rs_r * gg.z + bb.z;
        an.w = (a.w - mu_r) * rs_r * gg.w + bb.w;
        *(float4*)&As[lr][lc] = an;
        *(float4*)&Bs[lr][lc] = *(const float4*)(W + (size_t)(o0 + lr) * C_ + k0 + lc);
        __syncthreads();
        #pragma unroll
        for (int kk = 0; kk < 16; kk += 4) {
            float4 a4[4], b4[4];
            #pragma unroll
            for (int i = 0; i < 4; i++) a4[i] = *(const float4*)&As[ty + 16*i][kk];
            #pragma unroll
            for (int j = 0; j < 4; j++) b4[j] = *(const float4*)&Bs[tx + 16*j][kk];
            #pragma unroll
            for (int i = 0; i < 4; i++)
                #pragma unroll
                for (int j = 0; j < 4; j++)
                    acc[i][j] += a4[i].x*b4[j].x + a4[i].y*b4[j].y
                               + a4[i].z*b4[j].z + a4[i].w*b4[j].w;
        }
        __syncthreads();
    }
    #pragma unroll
    for (int i = 0; i < 4; i++) {
        int m = m0 + ty + 16*i;
        int b = m >> 10, n = m & 1023;
        #pragma unroll
        for (int j = 0; j < 4; j++) {
            int o = o0 + tx + 16*j;
            int h = o >> 6, d = o & 63;
            out[(((size_t)(b * H_ + h)) * N_ + n) * D_ + d] = acc[i][j] + bias[o];
        }
    }
}

// ---------------- scores: S[bh][n][m] = 0.125 * q[bh][n].k[bh][m]  (K=64) ----------------
__global__ __launch_bounds__(256)
void scores_kernel(const float* __restrict__ q, const float* __restrict__ k,
                   float* __restrict__ attn)
{
    int bh = blockIdx.z;
    int n0 = blockIdx.y * 64;
    int m0 = blockIdx.x * 64;
    const float* Q = q + (size_t)bh * N_ * D_;
    const float* K = k + (size_t)bh * N_ * D_;
    float* S = attn + (size_t)bh * NUMEL_;

    __shared__ float Qs[64][68];
    __shared__ float Ks[64][68];
    int tid = threadIdx.x;
    int lr = tid >> 2;
    int tx = tid & 15, ty = tid >> 4;

    #pragma unroll
    for (int p = 0; p < 4; p++) {
        int c = (tid & 3) * 16 + p * 4;
        *(float4*)&Qs[lr][c] = *(const float4*)(Q + (size_t)(n0 + lr) * D_ + c);
        *(float4*)&Ks[lr][c] = *(const float4*)(K + (size_t)(m0 + lr) * D_ + c);
    }
    __syncthreads();

    float acc[4][4] = {};
    #pragma unroll
    for (int kk = 0; kk < 64; kk += 4) {
        float4 a4[4], b4[4];
        #pragma unroll
        for (int i = 0; i < 4; i++) a4[i] = *(const float4*)&Qs[ty + 16*i][kk];
        #pragma unroll
        for (int j = 0; j < 4; j++) b4[j] = *(const float4*)&Ks[tx + 16*j][kk];
        #pragma unroll
        for (int i = 0; i < 4; i++)
            #pragma unroll
            for (int j = 0; j < 4; j++)
                acc[i][j] += a4[i].x*b4[j].x + a4[i].y*b4[j].y
                           + a4[i].z*b4[j].z + a4[i].w*b4[j].w;
    }
    #pragma unroll
    for (int i = 0; i < 4; i++)
        #pragma unroll
        for (int j = 0; j < 4; j++)
            S[(size_t)(n0 + ty + 16*i) * N_ + m0 + tx + 16*j] = acc[i][j] * 0.125f;
}

// ---------------- radix-select histogram pass ----------------
__global__ __launch_bounds__(256)
void hist_kernel(const float* __restrict__ scores, unsigned* __restrict__ hist,
                 const unsigned* __restrict__ prefix,
                 int shift, int nbins, int pshift, int use_prefix)
{
    __shared__ unsigned lh[2048];
    int bh = blockIdx.y;
    int split = blockIdx.x;
    int tid = threadIdx.x;
    for (int i = tid; i < nbins; i += 256) lh[i] = 0;
    __syncthreads();
    const float* S = scores + (size_t)bh * NUMEL_;
    int chunk = NUMEL_ / gridDim.x;
    const float4* src = (const float4*)(S + (size_t)split * chunk);
    unsigned pref = use_prefix ? prefix[bh] : 0u;
    unsigned mask = (unsigned)(nbins - 1);
    for (int i = tid; i < chunk / 4; i += 256) {
        float4 v = src[i];
        float f[4] = {v.x, v.y, v.z, v.w};
        #pragma unroll
        for (int c = 0; c < 4; c++) {
            unsigned key = f2key(f[c]);
            if (!use_prefix || (key >> pshift) == pref)
                atomicAdd(&lh[(key >> shift) & mask], 1u);
        }
    }
    __syncthreads();
    unsigned* gh = hist + (size_t)bh * 2048;
    for (int i = tid; i < nbins; i += 256)
        if (lh[i]) atomicAdd(&gh[i], lh[i]);
}

// ---------------- radix-select scan: find bin containing kth, update prefix/k or thr ----------------
__global__ __launch_bounds__(256)
void scan_kernel(const unsigned* __restrict__ hist, unsigned* __restrict__ kstate,
                 unsigned* __restrict__ prefix, float* __restrict__ thr,
                 int nbins, int mode)   // mode 0: init pass, 1: mid pass, 2: final
{
    int bh = blockIdx.x;
    const unsigned* h = hist + (size_t)bh * 2048;
    int tid = threadIdx.x;
    int per = nbins / 256;   // 8 or 4
    unsigned local[8];
    unsigned lsum = 0;
    for (int i = 0; i < per; i++) { local[i] = h[tid * per + i]; lsum += local[i]; }
    __shared__ unsigned ps[256];
    ps[tid] = lsum;
    __syncthreads();
    for (int off = 1; off < 256; off <<= 1) {
        unsigned add = (tid >= off) ? ps[tid - off] : 0u;
        __syncthreads();
        ps[tid] += add;
        __syncthreads();
    }
    unsigned k = (mode == 0) ? KSMALL_ : kstate[bh];
    unsigned before = (tid == 0) ? 0u : ps[tid - 1];
    if (before < k && k <= ps[tid]) {
        unsigned cum = before;
        for (int i = 0; i < per; i++) {
            if (k <= cum + local[i]) {
                int bin = tid * per + i;
                if (mode == 2) {
                    unsigned key = (prefix[bh] << 10) | (unsigned)bin;
                    unsigned u = (key & 0x80000000u) ? (key & 0x7FFFFFFFu) : ~key;
                    thr[bh] = __uint_as_float(u);
                } else {
                    prefix[bh] = (mode == 0) ? (unsigned)bin : ((prefix[bh] << 11) | (unsigned)bin);
                    kstate[bh] = k - cum;
                }
                break;
            }
            cum += local[i];
        }
    }
}

// ---------------- masked softmax, in place, one wave per row ----------------
__global__ __launch_bounds__(256)
void softmax_kernel(float* __restrict__ attn, const float* __restrict__ thr)
{
    int row  = blockIdx.x * 4 + (threadIdx.x >> 6);   // 65536 rows
    int lane = threadIdx.x & 63;
    float t = thr[row >> 10];
    float* p = attn + (size_t)row * N_;
    float4 v[4];
    float mx = -3.0e38f;
    #pragma unroll
    for (int i = 0; i < 4; i++) {
        v[i] = ((const float4*)p)[i * 64 + lane];
        v[i].x = (v[i].x < t) ? -10000.0f : fminf(fmaxf(v[i].x, -10000.0f), 10000.0f);
        v[i].y = (v[i].y < t) ? -10000.0f : fminf(fmaxf(v[i].y, -10000.0f), 10000.0f);
        v[i].z = (v[i].z < t) ? -10000.0f : fminf(fmaxf(v[i].z, -10000.0f), 10000.0f);
        v[i].w = (v[i].w < t) ? -10000.0f : fminf(fmaxf(v[i].w, -10000.0f), 10000.0f);
        mx = fmaxf(mx, fmaxf(fmaxf(v[i].x, v[i].y), fmaxf(v[i].z, v[i].w)));
    }
    #pragma unroll
    for (int off = 32; off; off >>= 1) mx = fmaxf(mx, __shfl_xor(mx, off));
    float s = 0.0f;
    #pragma unroll
    for (int i = 0; i < 4; i++) {
        v[i].x = expf(v[i].x - mx);
        v[i].y = expf(v[i].y - mx);
        v[i].z = expf(v[i].z - mx);
        v[i].w = expf(v[i].w - mx);
        s += v[i].x + v[i].y + v[i].z + v[i].w;
    }
    #pragma unroll
    for (int off = 32; off; off >>= 1) s += __shfl_xor(s, off);
    float inv = 1.0f / s;
    #pragma unroll
    for (int i = 0; i < 4; i++) {
        v[i].x *= inv; v[i].y *= inv; v[i].z *= inv; v[i].w *= inv;
        ((float4*)p)[i * 64 + lane] = v[i];
    }
}

// ---------------- x1[b,n,h*64+d] = sum_m attn[bh,n,m] * v[bh,m,d] ----------------
__global__ __launch_bounds__(256)
void attn_v_kernel(const float* __restrict__ attn, const float* __restrict__ v,
                   float* __restrict__ x1)
{
    int bh = blockIdx.y;
    int n0 = blockIdx.x * 64;
    const float* A = attn + (size_t)bh * NUMEL_;
    const float* V = v + (size_t)bh * N_ * D_;
    int b = bh >> 4, h = bh & 15;

    __shared__ float As[64][68];   // [n][m]
    __shared__ float Vs[64][68];   // transposed: [d][m]
    int tid = threadIdx.x;
    int lr = tid >> 2;
    int tx = tid & 15, ty = tid >> 4;

    float acc[4][4] = {};
    for (int k0 = 0; k0 < N_; k0 += 64) {
        #pragma unroll
        for (int p = 0; p < 4; p++) {
            int c = (tid & 3) * 16 + p * 4;
            *(float4*)&As[lr][c] = *(const float4*)(A + (size_t)(n0 + lr) * N_ + k0 + c);
            float4 vv = *(const float4*)(V + (size_t)(k0 + lr) * D_ + c);
            Vs[c + 0][lr] = vv.x; Vs[c + 1][lr] = vv.y;
            Vs[c + 2][lr] = vv.z; Vs[c + 3][lr] = vv.w;
        }
        __syncthreads();
        #pragma unroll
        for (int kk = 0; kk < 64; kk += 4) {
            float4 a4[4], b4[4];
            #pragma unroll
            for (int i = 0; i < 4; i++) a4[i] = *(const float4*)&As[ty + 16*i][kk];
            #pragma unroll
            for (int j = 0; j < 4; j++) b4[j] = *(const float4*)&Vs[tx + 16*j][kk];
            #pragma unroll
            for (int i = 0; i < 4; i++)
                #pragma unroll
                for (int j = 0; j < 4; j++)
                    acc[i][j] += a4[i].x*b4[j].x + a4[i].y*b4[j].y
                               + a4[i].z*b4[j].z + a4[i].w*b4[j].w;
        }
        __syncthreads();
    }
    #pragma unroll
    for (int i = 0; i < 4; i++) {
        int n = n0 + ty + 16*i;
        #pragma unroll
        for (int j = 0; j < 4; j++) {
            int d = tx + 16*j;
            x1[((size_t)(b * N_ + n)) * C_ + h * 64 + d] = acc[i][j];
        }
    }
}

// ---------------- x2 = x1 @ Wo^T + bo + identity ----------------
__global__ __launch_bounds__(256)
void outproj_kernel(const float* __restrict__ x1, const float* __restrict__ Wo,
                    const float* __restrict__ bo, const float* __restrict__ resid,
                    float* __restrict__ x2)
{
    int m0 = blockIdx.y * 64, o0 = blockIdx.x * 64;
    __shared__ float As[64][20];
    __shared__ float Bs[64][20];
    int tid = threadIdx.x;
    int lr = tid >> 2, lc = (tid & 3) * 4;
    int tx = tid & 15, ty = tid >> 4;
    float acc[4][4] = {};
    for (int k0 = 0; k0 < C_; k0 += 16) {
        *(float4*)&As[lr][lc] = *(const float4*)(x1 + (size_t)(m0 + lr) * C_ + k0 + lc);
        *(float4*)&Bs[lr][lc] = *(const float4*)(Wo + (size_t)(o0 + lr) * C_ + k0 + lc);
        __syncthreads();
        #pragma unroll
        for (int kk = 0; kk < 16; kk += 4) {
            float4 a4[4], b4[4];
            #pragma unroll
            for (int i = 0; i < 4; i++) a4[i] = *(const float4*)&As[ty + 16*i][kk];
            #pragma unroll
            for (int j = 0; j < 4; j++) b4[j] = *(const float4*)&Bs[tx + 16*j][kk];
            #pragma unroll
            for (int i = 0; i < 4; i++)
                #pragma unroll
                for (int j = 0; j < 4; j++)
                    acc[i][j] += a4[i].x*b4[j].x + a4[i].y*b4[j].y
                               + a4[i].z*b4[j].z + a4[i].w*b4[j].w;
        }
        __syncthreads();
    }
    #pragma unroll
    for (int i = 0; i < 4; i++) {
        int m = m0 + ty + 16*i;
        #pragma unroll
        for (int j = 0; j < 4; j++) {
            int o = o0 + tx + 16*j;
            x2[(size_t)m * C_ + o] = acc[i][j] + bo[o] + resid[(size_t)m * C_ + o];
        }
    }
}

// ---------------- final LN ----------------
__global__ __launch_bounds__(256)
void ln_out_kernel(const float* __restrict__ x2, const float* __restrict__ g,
                   const float* __restrict__ bta, float* __restrict__ out)
{
    int row = blockIdx.x, tid = threadIdx.x;
    float4 v = ((const float4*)(x2 + (size_t)row * C_))[tid];
    float s = v.x + v.y + v.z + v.w;
    float s2 = v.x*v.x + v.y*v.y + v.z*v.z + v.w*v.w;
    #pragma unroll
    for (int off = 32; off; off >>= 1) {
        s  += __shfl_down(s, off);
        s2 += __shfl_down(s2, off);
    }
    __shared__ float ls[4], ls2[4], bc[2];
    int wid = tid >> 6;
    if ((tid & 63) == 0) { ls[wid] = s; ls2[wid] = s2; }
    __syncthreads();
    if (tid == 0) {
        float S  = ls[0] + ls[1] + ls[2] + ls[3];
        float S2 = ls2[0] + ls2[1] + ls2[2] + ls2[3];
        float mu = S * (1.0f / C_);
        float var = S2 * (1.0f / C_) - mu * mu;
        bc[0] = mu;
        bc[1] = rsqrtf(var + EPS_);
    }
    __syncthreads();
    float mu = bc[0], rs = bc[1];
    float4 gg = ((const float4*)g)[tid];
    float4 bb = ((const float4*)bta)[tid];
    float4 o;
    o.x = (v.x - mu) * rs * gg.x + bb.x;
    o.y = (v.y - mu) * rs * gg.y + bb.y;
    o.z = (v.z - mu) * rs * gg.z + bb.z;
    o.w = (v.w - mu) * rs * gg.w + bb.w;
    ((float4*)(out + (size_t)row * C_))[tid] = o;
}

extern "C" void kernel_launch(void* const* d_in, const int* in_sizes, int n_in,
                              void* d_out, int out_size, void* d_ws, size_t ws_size,
                              hipStream_t stream) {
    (void)in_sizes; (void)n_in; (void)out_size; (void)ws_size;
    const float* qin  = (const float*)d_in[0];
    const float* kvin = (const float*)d_in[1];
    const float* g_q  = (const float*)d_in[2];
    const float* b_q  = (const float*)d_in[3];
    const float* g_k  = (const float*)d_in[4];
    const float* b_k  = (const float*)d_in[5];
    const float* g_v  = (const float*)d_in[6];
    const float* b_v  = (const float*)d_in[7];
    const float* Wq   = (const float*)d_in[8];
    const float* bq   = (const float*)d_in[9];
    const float* Wk   = (const float*)d_in[10];
    const float* bk   = (const float*)d_in[11];
    const float* Wv   = (const float*)d_in[12];
    const float* bv   = (const float*)d_in[13];
    const float* Wo   = (const float*)d_in[14];
    const float* bo   = (const float*)d_in[15];
    const float* g_out= (const float*)d_in[16];
    const float* b_out= (const float*)d_in[17];

    float* out_x    = (float*)d_out;
    float* out_attn = out_x + (size_t)BN_ * C_;   // 4194304 offset

    float* ws = (float*)d_ws;
    float* q_ws  = ws;                       // 4M floats
    float* k_ws  = ws + (size_t)4194304;     // 4M
    float* v_ws  = ws + (size_t)2 * 4194304; // 4M
    float* x1    = q_ws;                     // reuse q region after scores
    float* x2    = k_ws;                     // reuse k region after attn_v
    float* stats = ws + (size_t)3 * 4194304;           // 16384 floats
    unsigned* hist   = (unsigned*)(stats + 16384);     // 64*2048 uints
    unsigned* kstate = hist + 64 * 2048;               // 64
    unsigned* prefix = kstate + 64;                    // 64
    float*    thr    = (float*)(prefix + 64);          // 64

    // LN stats for both inputs
    ln_stats_kernel<<<2 * BN_, 256, 0, stream>>>(qin, kvin, stats);

    // Q/K/V projections (fused LN)
    proj_kernel<<<dim3(16, 64, 3), 256, 0, stream>>>(
        qin, kvin, stats, g_q, b_q, g_k, b_k, g_v, b_v,
        Wq, bq, Wk, bk, Wv, bv, q_ws, k_ws, v_ws);

    // raw scores into the attn output region
    scores_kernel<<<dim3(16, 16, 64), 256, 0, stream>>>(q_ws, k_ws, out_attn);

    // 3-pass radix select for per-(b,h) kth smallest
    hipMemsetAsync(hist, 0, 64 * 2048 * sizeof(unsigned), stream);
    hist_kernel<<<dim3(16, BH_), 256, 0, stream>>>(out_attn, hist, prefix, 21, 2048, 0, 0);
    scan_kernel<<<BH_, 256, 0, stream>>>(hist, kstate, prefix, thr, 2048, 0);
    hipMemsetAsync(hist, 0, 64 * 2048 * sizeof(unsigned), stream);
    hist_kernel<<<dim3(16, BH_), 256, 0, stream>>>(out_attn, hist, prefix, 10, 2048, 21, 1);
    scan_kernel<<<BH_, 256, 0, stream>>>(hist, kstate, prefix, thr, 2048, 1);
    hipMemsetAsync(hist, 0, 64 * 2048 * sizeof(unsigned), stream);
    hist_kernel<<<dim3(16, BH_), 256, 0, stream>>>(out_attn, hist, prefix, 0, 1024, 10, 1);
    scan_kernel<<<BH_, 256, 0, stream>>>(hist, kstate, prefix, thr, 1024, 2);

    // masked softmax in place
    softmax_kernel<<<(BH_ * N_) / 4, 256, 0, stream>>>(out_attn, thr);

    // attn @ V -> x1 [B,N,C]
    attn_v_kernel<<<dim3(16, BH_), 256, 0, stream>>>(out_attn, v_ws, x1);

    // output projection + residual
    outproj_kernel<<<dim3(16, 64), 256, 0, stream>>>(x1, Wo, bo, qin, x2);

    // final LN -> out_x
    ln_out_kernel<<<BN_, 256, 0, stream>>>(x2, g_out, b_out, out_x);
}

// Round 2
// 789.745 us; speedup vs baseline: 1.9333x; 1.9333x over previous
//
#include <hip/hip_runtime.h>
#include <math.h>

#define B_ 4
#define N_ 1024
#define C_ 1024
#define H_ 16
#define D_ 64
#define BN_ 4096
#define BH_ 64
#define NUMEL_ 1048576
#define KSMALL_ 104858u
#define EPS_ 1e-5f

typedef __attribute__((ext_vector_type(4))) float f32x4;
typedef __attribute__((ext_vector_type(8))) short s16x8;

__device__ __forceinline__ unsigned f2key(float f) {
    unsigned u = __float_as_uint(f);
    return (u & 0x80000000u) ? ~u : (u | 0x80000000u);
}

__device__ __forceinline__ unsigned short f2b(float f) {
    unsigned u = __float_as_uint(f);
    unsigned r = (u + 0x7FFFu + ((u >> 16) & 1u)) >> 16;
    return (unsigned short)r;
}

// ---------------- LN + bf16 convert: qn, kn, vn ----------------
__global__ __launch_bounds__(256)
void ln_bf16_kernel(const float* __restrict__ qin, const float* __restrict__ kvin,
                    const float* __restrict__ g_q, const float* __restrict__ b_q,
                    const float* __restrict__ g_k, const float* __restrict__ b_k,
                    const float* __restrict__ g_v, const float* __restrict__ b_v,
                    unsigned short* __restrict__ qn, unsigned short* __restrict__ kn,
                    unsigned short* __restrict__ vn)
{
    int row = blockIdx.x;     // 0..8191
    int t = threadIdx.x;
    bool is_q = row < BN_;
    int r = is_q ? row : row - BN_;
    const float* x = (is_q ? qin : kvin) + (size_t)r * C_;
    float4 v = ((const float4*)x)[t];
    float s = v.x + v.y + v.z + v.w;
    float s2 = v.x*v.x + v.y*v.y + v.z*v.z + v.w*v.w;
    #pragma unroll
    for (int off = 32; off; off >>= 1) {
        s  += __shfl_down(s, off);
        s2 += __shfl_down(s2, off);
    }
    __shared__ float ls[4], ls2[4], bc[2];
    int wid = t >> 6;
    if ((t & 63) == 0) { ls[wid] = s; ls2[wid] = s2; }
    __syncthreads();
    if (t == 0) {
        float S  = ls[0] + ls[1] + ls[2] + ls[3];
        float S2 = ls2[0] + ls2[1] + ls2[2] + ls2[3];
        float mu = S * (1.0f / C_);
        float var = S2 * (1.0f / C_) - mu * mu;
        bc[0] = mu; bc[1] = rsqrtf(var + EPS_);
    }
    __syncthreads();
    float mu = bc[0], rs = bc[1];
    if (is_q) {
        float4 gg = ((const float4*)g_q)[t];
        float4 bb = ((const float4*)b_q)[t];
        unsigned lo = (unsigned)f2b((v.x-mu)*rs*gg.x+bb.x) | ((unsigned)f2b((v.y-mu)*rs*gg.y+bb.y) << 16);
        unsigned hi = (unsigned)f2b((v.z-mu)*rs*gg.z+bb.z) | ((unsigned)f2b((v.w-mu)*rs*gg.w+bb.w) << 16);
        ((uint2*)(qn + (size_t)r * C_))[t] = make_uint2(lo, hi);
    } else {
        float4 gg = ((const float4*)g_k)[t];
        float4 bb = ((const float4*)b_k)[t];
        unsigned lo = (unsigned)f2b((v.x-mu)*rs*gg.x+bb.x) | ((unsigned)f2b((v.y-mu)*rs*gg.y+bb.y) << 16);
        unsigned hi = (unsigned)f2b((v.z-mu)*rs*gg.z+bb.z) | ((unsigned)f2b((v.w-mu)*rs*gg.w+bb.w) << 16);
        ((uint2*)(kn + (size_t)r * C_))[t] = make_uint2(lo, hi);
        gg = ((const float4*)g_v)[t];
        bb = ((const float4*)b_v)[t];
        lo = (unsigned)f2b((v.x-mu)*rs*gg.x+bb.x) | ((unsigned)f2b((v.y-mu)*rs*gg.y+bb.y) << 16);
        hi = (unsigned)f2b((v.z-mu)*rs*gg.z+bb.z) | ((unsigned)f2b((v.w-mu)*rs*gg.w+bb.w) << 16);
        ((uint2*)(vn + (size_t)r * C_))[t] = make_uint2(lo, hi);
    }
}

// ---------------- weight fp32 -> bf16 ----------------
__global__ __launch_bounds__(256)
void wcvt_kernel(const float* __restrict__ Wq, const float* __restrict__ Wk,
                 const float* __restrict__ Wv, const float* __restrict__ Wo,
                 unsigned short* __restrict__ out)
{
    int z = blockIdx.y;
    const float* W = (z == 0) ? Wq : (z == 1) ? Wk : (z == 2) ? Wv : Wo;
    unsigned short* dst = out + (size_t)z * (C_ * C_);
    int i = blockIdx.x * 256 + threadIdx.x;
    float4 v = ((const float4*)W)[i];
    unsigned lo = (unsigned)f2b(v.x) | ((unsigned)f2b(v.y) << 16);
    unsigned hi = (unsigned)f2b(v.z) | ((unsigned)f2b(v.w) << 16);
    ((uint2*)dst)[i] = make_uint2(lo, hi);
}

// ---------------- shared 128x128 MFMA GEMM core (both operands [idx][k] bf16) ----------------
__device__ __forceinline__ void gemm_core_128(
    const unsigned short* __restrict__ A, const unsigned short* __restrict__ Bt,
    int K, int lda, int ldb, int m0, int n0,
    unsigned short* As, unsigned short* Bs, f32x4 acc[4][4])
{
    int t = threadIdx.x;
    int srow = t >> 2, scol = (t & 3) * 8;
    int l = t & 63, w = t >> 6;
    int r15 = l & 15, q = l >> 4;
    int wm = (w & 1) * 64, wn = (w >> 1) * 64;
    for (int k0 = 0; k0 < K; k0 += 32) {
        __syncthreads();
        #pragma unroll
        for (int it = 0; it < 2; it++) {
            int r = srow + it * 64;
            *(uint4*)&As[r * 40 + scol] = *(const uint4*)(A  + (size_t)(m0 + r) * lda + k0 + scol);
            *(uint4*)&Bs[r * 40 + scol] = *(const uint4*)(Bt + (size_t)(n0 + r) * ldb + k0 + scol);
        }
        __syncthreads();
        s16x8 af[4], bfr[4];
        #pragma unroll
        for (int i = 0; i < 4; i++) af[i]  = *(const s16x8*)&As[(wm + i*16 + r15) * 40 + q * 8];
        #pragma unroll
        for (int j = 0; j < 4; j++) bfr[j] = *(const s16x8*)&Bs[(wn + j*16 + r15) * 40 + q * 8];
        #pragma unroll
        for (int i = 0; i < 4; i++)
            #pragma unroll
            for (int j = 0; j < 4; j++)
                acc[i][j] = __builtin_amdgcn_mfma_f32_16x16x32_bf16(af[i], bfr[j], acc[i][j], 0, 0, 0);
    }
}

// ---------------- Q/K projection: out bf16 [bh][n][d] ----------------
__global__ __launch_bounds__(256)
void gemm_qk_kernel(const unsigned short* __restrict__ qn, const unsigned short* __restrict__ kn,
                    const unsigned short* __restrict__ wbf,
                    const float* __restrict__ bq, const float* __restrict__ bk,
                    unsigned short* __restrict__ qb, unsigned short* __restrict__ kb)
{
    int z = blockIdx.z;
    const unsigned short* A = z ? kn : qn;
    const unsigned short* W = wbf + (size_t)z * (C_ * C_);
    const float* bias = z ? bk : bq;
    unsigned short* out = z ? kb : qb;
    int m0 = blockIdx.y * 128, n0 = blockIdx.x * 128;
    __shared__ unsigned short As[128 * 40], Bs[128 * 40];
    f32x4 acc[4][4];
    #pragma unroll
    for (int i = 0; i < 4; i++)
        #pragma unroll
        for (int j = 0; j < 4; j++) acc[i][j] = (f32x4){0.f, 0.f, 0.f, 0.f};
    gemm_core_128(A, W, C_, C_, C_, m0, n0, As, Bs, acc);
    int t = threadIdx.x, l = t & 63, w = t >> 6;
    int r15 = l & 15, q = l >> 4;
    int wm = (w & 1) * 64, wn = (w >> 1) * 64;
    #pragma unroll
    for (int i = 0; i < 4; i++)
        #pragma unroll
        for (int j = 0; j < 4; j++) {
            int gcol = n0 + wn + j * 16 + r15;
            float bsv = bias[gcol];
            int h = gcol >> 6, d = gcol & 63;
            #pragma unroll
            for (int e = 0; e < 4; e++) {
                int grow = m0 + wm + i * 16 + q * 4 + e;
                int b = grow >> 10, n = grow & 1023;
                out[(((size_t)(b * H_ + h)) * N_ + n) * D_ + d] = f2b(acc[i][j][e] + bsv);
            }
        }
}

// ---------------- V projection, transposed out: v_t bf16 [bh][d][n] ----------------
__global__ __launch_bounds__(256)
void gemm_vt_kernel(const unsigned short* __restrict__ wv, const unsigned short* __restrict__ vn,
                    const float* __restrict__ bv, unsigned short* __restrict__ vt)
{
    int m0 = blockIdx.y * 128;  // output channel o
    int n0 = blockIdx.x * 128;  // token
    __shared__ unsigned short As[128 * 40], Bs[128 * 40];
    f32x4 acc[4][4];
    #pragma unroll
    for (int i = 0; i < 4; i++)
        #pragma unroll
        for (int j = 0; j < 4; j++) acc[i][j] = (f32x4){0.f, 0.f, 0.f, 0.f};
    gemm_core_128(wv, vn, C_, C_, C_, m0, n0, As, Bs, acc);
    int t = threadIdx.x, l = t & 63, w = t >> 6;
    int r15 = l & 15, q = l >> 4;
    int wm = (w & 1) * 64, wn = (w >> 1) * 64;
    #pragma unroll
    for (int i = 0; i < 4; i++)
        #pragma unroll
        for (int j = 0; j < 4; j++) {
            int tok = n0 + wn + j * 16 + r15;
            int b = tok >> 10, nn = tok & 1023;
            #pragma unroll
            for (int e = 0; e < 4; e++) {
                int o = m0 + wm + i * 16 + q * 4 + e;
                int h = o >> 6, d = o & 63;
                vt[(((size_t)(b * H_ + h)) * D_ + d) * N_ + nn] = f2b(acc[i][j][e] + bv[o]);
            }
        }
}

// ---------------- scores: fp32 out ----------------
__global__ __launch_bounds__(256)
void gemm_scores_kernel(const unsigned short* __restrict__ qb, const unsigned short* __restrict__ kb,
                        float* __restrict__ attn)
{
    int bh = blockIdx.z;
    int m0 = blockIdx.y * 128, n0 = blockIdx.x * 128;
    const unsigned short* Q = qb + (size_t)bh * N_ * D_;
    const unsigned short* K = kb + (size_t)bh * N_ * D_;
    float* S = attn + (size_t)bh * NUMEL_;
    __shared__ unsigned short As[128 * 40], Bs[128 * 40];
    f32x4 acc[4][4];
    #pragma unroll
    for (int i = 0; i < 4; i++)
        #pragma unroll
        for (int j = 0; j < 4; j++) acc[i][j] = (f32x4){0.f, 0.f, 0.f, 0.f};
    gemm_core_128(Q, K, D_, D_, D_, m0, n0, As, Bs, acc);
    int t = threadIdx.x, l = t & 63, w = t >> 6;
    int r15 = l & 15, q = l >> 4;
    int wm = (w & 1) * 64, wn = (w >> 1) * 64;
    #pragma unroll
    for (int i = 0; i < 4; i++)
        #pragma unroll
        for (int j = 0; j < 4; j++) {
            int gcol = n0 + wn + j * 16 + r15;
            #pragma unroll
            for (int e = 0; e < 4; e++) {
                int grow = m0 + wm + i * 16 + q * 4 + e;
                S[(size_t)grow * N_ + gcol] = acc[i][j][e] * 0.125f;
            }
        }
}

// ---------------- attn @ V: A fp32 attn (cvt in staging), B = v_t, out x1 bf16 ----------------
__global__ __launch_bounds__(256)
void gemm_av_kernel(const float* __restrict__ attn, const unsigned short* __restrict__ vt,
                    unsigned short* __restrict__ x1)
{
    int bh = blockIdx.y;
    int n0 = blockIdx.x * 128;   // query rows
    const float* Ag = attn + (size_t)bh * NUMEL_;
    const unsigned short* Bg = vt + (size_t)bh * D_ * N_;
    __shared__ unsigned short As[128 * 40];
    __shared__ unsigned short Bs[64 * 40];
    f32x4 acc[2][4];
    #pragma unroll
    for (int i = 0; i < 2; i++)
        #pragma unroll
        for (int j = 0; j < 4; j++) acc[i][j] = (f32x4){0.f, 0.f, 0.f, 0.f};
    int t = threadIdx.x, l = t & 63, w = t >> 6;
    int r15 = l & 15, q = l >> 4;
    int wm = w * 32;
    int arow = t >> 3, acol = (t & 7) * 4;
    int brow = t >> 2, bcol = (t & 3) * 8;
    for (int k0 = 0; k0 < N_; k0 += 32) {
        __syncthreads();
        #pragma unroll
        for (int it = 0; it < 4; it++) {
            int r = arow + it * 32;
            float4 v = *(const float4*)(Ag + (size_t)(n0 + r) * N_ + k0 + acol);
            unsigned lo = (unsigned)f2b(v.x) | ((unsigned)f2b(v.y) << 16);
            unsigned hi = (unsigned)f2b(v.z) | ((unsigned)f2b(v.w) << 16);
            *(uint2*)&As[r * 40 + acol] = make_uint2(lo, hi);
        }
        *(uint4*)&Bs[brow * 40 + bcol] = *(const uint4*)(Bg + (size_t)brow * N_ + k0 + bcol);
        __syncthreads();
        s16x8 af[2], bfr[4];
        #pragma unroll
        for (int i = 0; i < 2; i++) af[i]  = *(const s16x8*)&As[(wm + i*16 + r15) * 40 + q * 8];
        #pragma unroll
        for (int j = 0; j < 4; j++) bfr[j] = *(const s16x8*)&Bs[(j*16 + r15) * 40 + q * 8];
        #pragma unroll
        for (int i = 0; i < 2; i++)
            #pragma unroll
            for (int j = 0; j < 4; j++)
                acc[i][j] = __builtin_amdgcn_mfma_f32_16x16x32_bf16(af[i], bfr[j], acc[i][j], 0, 0, 0);
    }
    int b = bh >> 4, h = bh & 15;
    #pragma unroll
    for (int i = 0; i < 2; i++)
        #pragma unroll
        for (int j = 0; j < 4; j++) {
            int d = j * 16 + r15;
            #pragma unroll
            for (int e = 0; e < 4; e++) {
                int n = n0 + wm + i * 16 + q * 4 + e;
                x1[((size_t)(b * N_ + n)) * C_ + h * D_ + d] = f2b(acc[i][j][e]);
            }
        }
}

// ---------------- out projection: fp32 out + bias + residual ----------------
__global__ __launch_bounds__(256)
void gemm_out_kernel(const unsigned short* __restrict__ x1, const unsigned short* __restrict__ wo,
                     const float* __restrict__ bo, const float* __restrict__ resid,
                     float* __restrict__ x2)
{
    int m0 = blockIdx.y * 128, n0 = blockIdx.x * 128;
    __shared__ unsigned short As[128 * 40], Bs[128 * 40];
    f32x4 acc[4][4];
    #pragma unroll
    for (int i = 0; i < 4; i++)
        #pragma unroll
        for (int j = 0; j < 4; j++) acc[i][j] = (f32x4){0.f, 0.f, 0.f, 0.f};
    gemm_core_128(x1, wo, C_, C_, C_, m0, n0, As, Bs, acc);
    int t = threadIdx.x, l = t & 63, w = t >> 6;
    int r15 = l & 15, q = l >> 4;
    int wm = (w & 1) * 64, wn = (w >> 1) * 64;
    #pragma unroll
    for (int i = 0; i < 4; i++)
        #pragma unroll
        for (int j = 0; j < 4; j++) {
            int gcol = n0 + wn + j * 16 + r15;
            float bsv = bo[gcol];
            #pragma unroll
            for (int e = 0; e < 4; e++) {
                int grow = m0 + wm + i * 16 + q * 4 + e;
                x2[(size_t)grow * C_ + gcol] = acc[i][j][e] + bsv + resid[(size_t)grow * C_ + gcol];
            }
        }
}

// ---------------- radix-select histogram pass ----------------
__global__ __launch_bounds__(256)
void hist_kernel(const float* __restrict__ scores, unsigned* __restrict__ hist,
                 const unsigned* __restrict__ prefix,
                 int shift, int nbins, int pshift, int use_prefix)
{
    __shared__ unsigned lh[2048];
    int bh = blockIdx.y;
    int split = blockIdx.x;
    int tid = threadIdx.x;
    for (int i = tid; i < nbins; i += 256) lh[i] = 0;
    __syncthreads();
    const float* S = scores + (size_t)bh * NUMEL_;
    int chunk = NUMEL_ / gridDim.x;
    const float4* src = (const float4*)(S + (size_t)split * chunk);
    unsigned pref = use_prefix ? prefix[bh] : 0u;
    unsigned mask = (unsigned)(nbins - 1);
    for (int i = tid; i < chunk / 4; i += 256) {
        float4 v = src[i];
        float f[4] = {v.x, v.y, v.z, v.w};
        #pragma unroll
        for (int c = 0; c < 4; c++) {
            unsigned key = f2key(f[c]);
            if (!use_prefix || (key >> pshift) == pref)
                atomicAdd(&lh[(key >> shift) & mask], 1u);
        }
    }
    __syncthreads();
    unsigned* gh = hist + (size_t)bh * 2048;
    for (int i = tid; i < nbins; i += 256)
        if (lh[i]) atomicAdd(&gh[i], lh[i]);
}

// ---------------- radix-select scan ----------------
__global__ __launch_bounds__(256)
void scan_kernel(const unsigned* __restrict__ hist, unsigned* __restrict__ kstate,
                 unsigned* __restrict__ prefix, float* __restrict__ thr,
                 int nbins, int mode)
{
    int bh = blockIdx.x;
    const unsigned* h = hist + (size_t)bh * 2048;
    int tid = threadIdx.x;
    int per = nbins / 256;
    unsigned local[8];
    unsigned lsum = 0;
    for (int i = 0; i < per; i++) { local[i] = h[tid * per + i]; lsum += local[i]; }
    __shared__ unsigned ps[256];
    ps[tid] = lsum;
    __syncthreads();
    for (int off = 1; off < 256; off <<= 1) {
        unsigned add = (tid >= off) ? ps[tid - off] : 0u;
        __syncthreads();
        ps[tid] += add;
        __syncthreads();
    }
    unsigned k = (mode == 0) ? KSMALL_ : kstate[bh];
    unsigned before = (tid == 0) ? 0u : ps[tid - 1];
    if (before < k && k <= ps[tid]) {
        unsigned cum = before;
        for (int i = 0; i < per; i++) {
            if (k <= cum + local[i]) {
                int bin = tid * per + i;
                if (mode == 2) {
                    unsigned key = (prefix[bh] << 10) | (unsigned)bin;
                    unsigned u = (key & 0x80000000u) ? (key & 0x7FFFFFFFu) : ~key;
                    thr[bh] = __uint_as_float(u);
                } else {
                    prefix[bh] = (mode == 0) ? (unsigned)bin : ((prefix[bh] << 11) | (unsigned)bin);
                    kstate[bh] = k - cum;
                }
                break;
            }
            cum += local[i];
        }
    }
}

// ---------------- masked softmax, in place ----------------
__global__ __launch_bounds__(256)
void softmax_kernel(float* __restrict__ attn, const float* __restrict__ thr)
{
    int row  = blockIdx.x * 4 + (threadIdx.x >> 6);
    int lane = threadIdx.x & 63;
    float t = thr[row >> 10];
    float* p = attn + (size_t)row * N_;
    float4 v[4];
    float mx = -3.0e38f;
    #pragma unroll
    for (int i = 0; i < 4; i++) {
        v[i] = ((const float4*)p)[i * 64 + lane];
        v[i].x = (v[i].x < t) ? -10000.0f : fminf(fmaxf(v[i].x, -10000.0f), 10000.0f);
        v[i].y = (v[i].y < t) ? -10000.0f : fminf(fmaxf(v[i].y, -10000.0f), 10000.0f);
        v[i].z = (v[i].z < t) ? -10000.0f : fminf(fmaxf(v[i].z, -10000.0f), 10000.0f);
        v[i].w = (v[i].w < t) ? -10000.0f : fminf(fmaxf(v[i].w, -10000.0f), 10000.0f);
        mx = fmaxf(mx, fmaxf(fmaxf(v[i].x, v[i].y), fmaxf(v[i].z, v[i].w)));
    }
    #pragma unroll
    for (int off = 32; off; off >>= 1) mx = fmaxf(mx, __shfl_xor(mx, off));
    float s = 0.0f;
    #pragma unroll
    for (int i = 0; i < 4; i++) {
        v[i].x = expf(v[i].x - mx);
        v[i].y = expf(v[i].y - mx);
        v[i].z = expf(v[i].z - mx);
        v[i].w = expf(v[i].w - mx);
        s += v[i].x + v[i].y + v[i].z + v[i].w;
    }
    #pragma unroll
    for (int off = 32; off; off >>= 1) s += __shfl_xor(s, off);
    float inv = 1.0f / s;
    #pragma unroll
    for (int i = 0; i < 4; i++) {
        v[i].x *= inv; v[i].y *= inv; v[i].z *= inv; v[i].w *= inv;
        ((float4*)p)[i * 64 + lane] = v[i];
    }
}

// ---------------- final LN ----------------
__global__ __launch_bounds__(256)
void ln_out_kernel(const float* __restrict__ x2, const float* __restrict__ g,
                   const float* __restrict__ bta, float* __restrict__ out)
{
    int row = blockIdx.x, tid = threadIdx.x;
    float4 v = ((const float4*)(x2 + (size_t)row * C_))[tid];
    float s = v.x + v.y + v.z + v.w;
    float s2 = v.x*v.x + v.y*v.y + v.z*v.z + v.w*v.w;
    #pragma unroll
    for (int off = 32; off; off >>= 1) {
        s  += __shfl_down(s, off);
        s2 += __shfl_down(s2, off);
    }
    __shared__ float ls[4], ls2[4], bc[2];
    int wid = tid >> 6;
    if ((tid & 63) == 0) { ls[wid] = s; ls2[wid] = s2; }
    __syncthreads();
    if (tid == 0) {
        float S  = ls[0] + ls[1] + ls[2] + ls[3];
        float S2 = ls2[0] + ls2[1] + ls2[2] + ls2[3];
        float mu = S * (1.0f / C_);
        float var = S2 * (1.0f / C_) - mu * mu;
        bc[0] = mu;
        bc[1] = rsqrtf(var + EPS_);
    }
    __syncthreads();
    float mu = bc[0], rs = bc[1];
    float4 gg = ((const float4*)g)[tid];
    float4 bb = ((const float4*)bta)[tid];
    float4 o;
    o.x = (v.x - mu) * rs * gg.x + bb.x;
    o.y = (v.y - mu) * rs * gg.y + bb.y;
    o.z = (v.z - mu) * rs * gg.z + bb.z;
    o.w = (v.w - mu) * rs * gg.w + bb.w;
    ((float4*)(out + (size_t)row * C_))[tid] = o;
}

extern "C" void kernel_launch(void* const* d_in, const int* in_sizes, int n_in,
                              void* d_out, int out_size, void* d_ws, size_t ws_size,
                              hipStream_t stream) {
    (void)in_sizes; (void)n_in; (void)out_size; (void)ws_size;
    const float* qin  = (const float*)d_in[0];
    const float* kvin = (const float*)d_in[1];
    const float* g_q  = (const float*)d_in[2];
    const float* b_q  = (const float*)d_in[3];
    const float* g_k  = (const float*)d_in[4];
    const float* b_k  = (const float*)d_in[5];
    const float* g_v  = (const float*)d_in[6];
    const float* b_v  = (const float*)d_in[7];
    const float* Wq   = (const float*)d_in[8];
    const float* bq   = (const float*)d_in[9];
    const float* Wk   = (const float*)d_in[10];
    const float* bk   = (const float*)d_in[11];
    const float* Wv   = (const float*)d_in[12];
    const float* bv   = (const float*)d_in[13];
    const float* Wo   = (const float*)d_in[14];
    const float* bo   = (const float*)d_in[15];
    const float* g_out= (const float*)d_in[16];
    const float* b_out= (const float*)d_in[17];

    float* out_x    = (float*)d_out;
    float* out_attn = out_x + (size_t)BN_ * C_;

    char* ws = (char*)d_ws;
    unsigned short* qn  = (unsigned short*)(ws);                        // 8 MB
    unsigned short* kn  = (unsigned short*)(ws + ((size_t)8  << 20));   // 8 MB
    unsigned short* vn  = (unsigned short*)(ws + ((size_t)16 << 20));   // 8 MB
    unsigned short* wbf = (unsigned short*)(ws + ((size_t)24 << 20));   // 4x2 MB (wq,wk,wv,wo)
    unsigned short* qb  = (unsigned short*)(ws + ((size_t)32 << 20));   // 8 MB
    unsigned short* kb  = (unsigned short*)(ws + ((size_t)40 << 20));   // 8 MB
    unsigned short* vt  = (unsigned short*)(ws);                        // alias qn (dead)
    unsigned short* x1  = (unsigned short*)(ws + ((size_t)8  << 20));   // alias kn (dead)
    float*          x2  = (float*)(ws + ((size_t)32 << 20));            // alias qb/kb (dead)
    unsigned* hist   = (unsigned*)(ws + ((size_t)48 << 20));            // 512 KB
    unsigned* kstate = hist + 64 * 2048;
    unsigned* prefix = kstate + 64;
    float*    thr    = (float*)(prefix + 64);

    // LN + bf16 conversion
    ln_bf16_kernel<<<2 * BN_, 256, 0, stream>>>(qin, kvin, g_q, b_q, g_k, b_k, g_v, b_v, qn, kn, vn);
    wcvt_kernel<<<dim3(1024, 4), 256, 0, stream>>>(Wq, Wk, Wv, Wo, wbf);

    // projections (MFMA)
    gemm_qk_kernel<<<dim3(8, 32, 2), 256, 0, stream>>>(qn, kn, wbf, bq, bk, qb, kb);
    gemm_vt_kernel<<<dim3(32, 8), 256, 0, stream>>>(wbf + (size_t)2 * C_ * C_, vn, bv, vt);

    // scores (MFMA) into attn output region
    gemm_scores_kernel<<<dim3(8, 8, 64), 256, 0, stream>>>(qb, kb, out_attn);

    // 3-pass radix select
    hipMemsetAsync(hist, 0, 64 * 2048 * sizeof(unsigned), stream);
    hist_kernel<<<dim3(16, BH_), 256, 0, stream>>>(out_attn, hist, prefix, 21, 2048, 0, 0);
    scan_kernel<<<BH_, 256, 0, stream>>>(hist, kstate, prefix, thr, 2048, 0);
    hipMemsetAsync(hist, 0, 64 * 2048 * sizeof(unsigned), stream);
    hist_kernel<<<dim3(16, BH_), 256, 0, stream>>>(out_attn, hist, prefix, 10, 2048, 21, 1);
    scan_kernel<<<BH_, 256, 0, stream>>>(hist, kstate, prefix, thr, 2048, 1);
    hipMemsetAsync(hist, 0, 64 * 2048 * sizeof(unsigned), stream);
    hist_kernel<<<dim3(16, BH_), 256, 0, stream>>>(out_attn, hist, prefix, 0, 1024, 10, 1);
    scan_kernel<<<BH_, 256, 0, stream>>>(hist, kstate, prefix, thr, 1024, 2);

    // masked softmax in place
    softmax_kernel<<<(BH_ * N_) / 4, 256, 0, stream>>>(out_attn, thr);

    // attn @ V (MFMA) -> x1 bf16
    gemm_av_kernel<<<dim3(8, BH_), 256, 0, stream>>>(out_attn, vt, x1);

    // output projection + residual (MFMA)
    gemm_out_kernel<<<dim3(8, 32), 256, 0, stream>>>(x1, wbf + (size_t)3 * C_ * C_, bo, qin, x2);

    // final LN
    ln_out_kernel<<<BN_, 256, 0, stream>>>(x2, g_out, b_out, out_x);
}